// Round 1
// baseline (681.420 us; speedup 1.0000x reference)
//
#include <hip/hip_runtime.h>

// GNNTEP: 3x {GCN(win->nh) + BN + min-skip + GCN(nh->nh) + BN + min} -> FC
// Key restructurings:
//  - adj@X shared across the 3 iterations (computed once).
//  - BN folded into rescaled adjacency (adjB[n,m]=adj[n,m]*a[m]) + row const rc[n].
//  - bf16 MFMA (16x16x32) for all matmuls; fp32 epilogues/stats/min/FC.

typedef short  s16x8 __attribute__((ext_vector_type(8)));
typedef float  f32x4 __attribute__((ext_vector_type(4)));

#define NN   512
#define NB   1024
#define NH   64
#define LDT  72   // LDS row stride (elements) -> 2-way-max bank aliasing on b128

#define MFMA16(a, b, c) __builtin_amdgcn_mfma_f32_16x16x32_bf16((a), (b), (c), 0, 0, 0)

__device__ __forceinline__ unsigned short f2bf(float f) {
  union { float f; unsigned u; } v; v.f = f;
  unsigned r = v.u + 0x7fffu + ((v.u >> 16) & 1u);   // RNE
  return (unsigned short)(r >> 16);
}
__device__ __forceinline__ float bf2f(unsigned short h) {
  union { unsigned u; float f; } v; v.u = ((unsigned)h) << 16;
  return v.f;
}

// ---------------- prep ----------------
__global__ void k_prep_adj(const float* __restrict__ adj, unsigned short* __restrict__ adjbf) {
  int idx = blockIdx.x * 256 + threadIdx.x;        // 512*512
  int n = idx >> 9, m = idx & 511;
  float v = adj[idx];
  if (n == m) v = 0.f;
  adjbf[idx] = f2bf(v);
}

// W1t[i][f][w] = W1[i][w][f];  W2t[i][d][f] = W2[i][f][d]
__global__ void k_prep_w(const float* __restrict__ W1, const float* __restrict__ W2,
                         unsigned short* __restrict__ W1t, unsigned short* __restrict__ W2t) {
  int idx = blockIdx.x * 256 + threadIdx.x;        // 3*64*64
  int i = idx >> 12, rc_ = idx & 4095;
  int src = (i << 12) + ((rc_ & 63) << 6) + (rc_ >> 6);
  W1t[idx] = f2bf(W1[src]);
  W2t[idx] = f2bf(W2[src]);
}

// X[b][m][w] f32 -> Xt[b][w][m] bf16 (per-block 64x64 tile via LDS)
__global__ __launch_bounds__(256)
void k_transpose_x(const float* __restrict__ X, unsigned short* __restrict__ Xt) {
  __shared__ unsigned short T[64 * LDT];
  int blk = blockIdx.x; int b = blk >> 3; int m0 = (blk & 7) << 6;
  int t = threadIdx.x; int r = t >> 2, seg = t & 3;
  const float* src = X + ((size_t)b * NN + m0 + r) * NH + seg * 16;
#pragma unroll
  for (int e = 0; e < 16; ++e) T[(seg * 16 + e) * LDT + r] = f2bf(src[e]);
  __syncthreads();
  unsigned short* dst = Xt + ((size_t)b * NH + r) * NN + m0 + seg * 16;
  const unsigned short* sT = &T[r * LDT + seg * 16];
  *(s16x8*)dst       = *(const s16x8*)sT;
  *(s16x8*)(dst + 8) = *(const s16x8*)(sT + 8);
}

// ---------------- AX = adj @ X  (per b: D[i=w][j=n] = sum_m Xt[w][m] * adj[n][m]) ----------------
__global__ __launch_bounds__(256)
void k_gemm_ax(const unsigned short* __restrict__ Xt, const unsigned short* __restrict__ adjbf,
               unsigned short* __restrict__ AX) {
  __shared__ unsigned short At[64 * LDT];   // Xt rows (w), k = m
  __shared__ unsigned short Bt[64 * LDT];   // adj rows (n), k = m
  int blk = blockIdx.x; int b = blk >> 3; int n0 = (blk & 7) << 6;
  int t = threadIdx.x, lane = t & 63, wid = t >> 6;
  int wi = wid >> 1, wj = wid & 1;
  int r = t >> 2, seg = t & 3;
  const unsigned short* aSrc = Xt + ((size_t)b * NH + r) * NN + seg * 16;
  const unsigned short* bSrc = adjbf + (size_t)(n0 + r) * NN + seg * 16;
  unsigned short* aDst = &At[r * LDT + seg * 16];
  unsigned short* bDst = &Bt[r * LDT + seg * 16];

  f32x4 acc[2][2] = {};
  for (int kt = 0; kt < 8; ++kt) {
    __syncthreads();
    *(s16x8*)aDst = *(const s16x8*)aSrc;  *(s16x8*)(aDst + 8) = *(const s16x8*)(aSrc + 8);
    *(s16x8*)bDst = *(const s16x8*)bSrc;  *(s16x8*)(bDst + 8) = *(const s16x8*)(bSrc + 8);
    aSrc += 64; bSrc += 64;
    __syncthreads();
#pragma unroll
    for (int kk = 0; kk < 2; ++kk) {
      int ko = kk * 32 + (lane >> 4) * 8;
      s16x8 a0 = *(const s16x8*)&At[(wi * 32 +  0 + (lane & 15)) * LDT + ko];
      s16x8 a1 = *(const s16x8*)&At[(wi * 32 + 16 + (lane & 15)) * LDT + ko];
      s16x8 b0 = *(const s16x8*)&Bt[(wj * 32 +  0 + (lane & 15)) * LDT + ko];
      s16x8 b1 = *(const s16x8*)&Bt[(wj * 32 + 16 + (lane & 15)) * LDT + ko];
      acc[0][0] = MFMA16(a0, b0, acc[0][0]);
      acc[1][0] = MFMA16(a1, b0, acc[1][0]);
      acc[0][1] = MFMA16(a0, b1, acc[0][1]);
      acc[1][1] = MFMA16(a1, b1, acc[1][1]);
    }
  }
  // D[i=w][j=n] -> AX[b][n][w] (lane: col n fixed, 4 consecutive w)
  int colb = n0 + wj * 32 + (lane & 15);
  int rowb = wi * 32 + (lane >> 4) * 4;
#pragma unroll
  for (int fi = 0; fi < 2; ++fi)
#pragma unroll
    for (int fj = 0; fj < 2; ++fj) {
      int n = colb + fj * 16, w = rowb + fi * 16;
      ushort4 pk;
      pk.x = f2bf(acc[fi][fj][0]); pk.y = f2bf(acc[fi][fj][1]);
      pk.z = f2bf(acc[fi][fj][2]); pk.w = f2bf(acc[fi][fj][3]);
      *(ushort4*)&AX[((size_t)b * NN + n) * NH + w] = pk;
    }
}

// ---------------- H1t = relu(AX @ W1 + b1), + per-node stats ----------------
// D[i=n][j=f]; A = AX rows n (k=w), B = W1t rows f (k=w). Out H1t[b][f][n].
__global__ __launch_bounds__(256)
void k_h1(const unsigned short* __restrict__ AX, const unsigned short* __restrict__ W1t_i,
          const float* __restrict__ b1_i, unsigned short* __restrict__ H1t,
          float* __restrict__ Ssum, float* __restrict__ Ssq) {
  __shared__ unsigned short At[64 * LDT];
  __shared__ unsigned short Bt[64 * LDT];
  __shared__ float ssum[64], ssq[64];
  int blk = blockIdx.x; int b = blk >> 3; int n0 = (blk & 7) << 6;
  int t = threadIdx.x, lane = t & 63, wid = t >> 6;
  int wi = wid >> 1, wj = wid & 1;
  int r = t >> 2, seg = t & 3;
  if (t < 64) { ssum[t] = 0.f; ssq[t] = 0.f; }
  {
    const unsigned short* aSrc = AX + ((size_t)b * NN + n0 + r) * NH + seg * 16;
    const unsigned short* bSrc = W1t_i + r * 64 + seg * 16;
    *(s16x8*)&At[r * LDT + seg * 16] = *(const s16x8*)aSrc;
    *(s16x8*)&At[r * LDT + seg * 16 + 8] = *(const s16x8*)(aSrc + 8);
    *(s16x8*)&Bt[r * LDT + seg * 16] = *(const s16x8*)bSrc;
    *(s16x8*)&Bt[r * LDT + seg * 16 + 8] = *(const s16x8*)(bSrc + 8);
  }
  __syncthreads();
  f32x4 acc[2][2] = {};
#pragma unroll
  for (int kk = 0; kk < 2; ++kk) {
    int ko = kk * 32 + (lane >> 4) * 8;
    s16x8 a0 = *(const s16x8*)&At[(wi * 32 +  0 + (lane & 15)) * LDT + ko];
    s16x8 a1 = *(const s16x8*)&At[(wi * 32 + 16 + (lane & 15)) * LDT + ko];
    s16x8 b0 = *(const s16x8*)&Bt[(wj * 32 +  0 + (lane & 15)) * LDT + ko];
    s16x8 b1 = *(const s16x8*)&Bt[(wj * 32 + 16 + (lane & 15)) * LDT + ko];
    acc[0][0] = MFMA16(a0, b0, acc[0][0]);
    acc[1][0] = MFMA16(a1, b0, acc[1][0]);
    acc[0][1] = MFMA16(a0, b1, acc[0][1]);
    acc[1][1] = MFMA16(a1, b1, acc[1][1]);
  }
  int fcol = wj * 32 + (lane & 15);
  float bia0 = b1_i[fcol], bia1 = b1_i[fcol + 16];
#pragma unroll
  for (int fi = 0; fi < 2; ++fi) {
    int nloc = wi * 32 + fi * 16 + (lane >> 4) * 4;
    float v0[4], v1[4];
#pragma unroll
    for (int rr = 0; rr < 4; ++rr) {
      float x0 = fmaxf(acc[fi][0][rr] + bia0, 0.f);
      float x1 = fmaxf(acc[fi][1][rr] + bia1, 0.f);
      v0[rr] = x0; v1[rr] = x1;
      float sv = x0 + x1, qv = x0 * x0 + x1 * x1;
      sv += __shfl_xor(sv, 1); sv += __shfl_xor(sv, 2); sv += __shfl_xor(sv, 4); sv += __shfl_xor(sv, 8);
      qv += __shfl_xor(qv, 1); qv += __shfl_xor(qv, 2); qv += __shfl_xor(qv, 4); qv += __shfl_xor(qv, 8);
      if ((lane & 15) == 0) { atomicAdd(&ssum[nloc + rr], sv); atomicAdd(&ssq[nloc + rr], qv); }
    }
    ushort4 p0, p1;
    p0.x = f2bf(v0[0]); p0.y = f2bf(v0[1]); p0.z = f2bf(v0[2]); p0.w = f2bf(v0[3]);
    p1.x = f2bf(v1[0]); p1.y = f2bf(v1[1]); p1.z = f2bf(v1[2]); p1.w = f2bf(v1[3]);
    *(ushort4*)&H1t[((size_t)b * NH + fcol)      * NN + n0 + nloc] = p0;
    *(ushort4*)&H1t[((size_t)b * NH + fcol + 16) * NN + n0 + nloc] = p1;
  }
  __syncthreads();
  if (t < 64) { atomicAdd(&Ssum[n0 + t], ssum[t]); atomicAdd(&Ssq[n0 + t], ssq[t]); }
}

// ---------------- finalize BN: a = g*rsqrt(var+eps), c = be - mean*a ----------------
__global__ void k_finalize(const float* __restrict__ Ssum, const float* __restrict__ Ssq,
                           const float* __restrict__ g, const float* __restrict__ be,
                           float* __restrict__ A, float* __restrict__ C) {
  int n = blockIdx.x * 256 + threadIdx.x;   // 512
  float mean = Ssum[n] * (1.f / 65536.f);
  float var  = Ssq[n] * (1.f / 65536.f) - mean * mean;
  float a = g[n] * rsqrtf(var + 1e-5f);
  A[n] = a; C[n] = be[n] - mean * a;
}

// ---------------- adjB[n][m] = adj[n][m]*a[m]; rc[n] = sum_m adj[n][m]*c[m] ----------------
__global__ __launch_bounds__(256)
void k_adjb(const unsigned short* __restrict__ adjbf, const float* __restrict__ A1,
            const float* __restrict__ C1, unsigned short* __restrict__ adjB,
            float* __restrict__ rc) {
  __shared__ float red[256];
  int n = blockIdx.x, t = threadIdx.x;
  float acc = 0.f;
#pragma unroll
  for (int hh = 0; hh < 2; ++hh) {
    int m = t + hh * 256;
    float av = bf2f(adjbf[n * NN + m]);
    adjB[n * NN + m] = f2bf(av * A1[m]);
    acc += av * C1[m];
  }
  red[t] = acc; __syncthreads();
  for (int s = 128; s > 0; s >>= 1) { if (t < s) red[t] += red[t + s]; __syncthreads(); }
  if (t == 0) rc[n] = red[0];
}

// ---------------- row-min over nodes of a[n]*h+c[n] (wave per (b,feat) row) ----------------
__global__ __launch_bounds__(256)
void k_minrow_skip(const unsigned short* __restrict__ Ht, const float* __restrict__ A1,
                   const float* __restrict__ C1, float* __restrict__ skip_i) {
  int t = threadIdx.x, lane = t & 63, wid = t >> 6;
  int row = blockIdx.x * 4 + wid;          // b*64 + f
  s16x8 hv = *(const s16x8*)(Ht + (size_t)row * NN + lane * 8);
  const float* ap = A1 + lane * 8;
  const float* cp = C1 + lane * 8;
  float m = 1e30f;
#pragma unroll
  for (int e = 0; e < 8; ++e) m = fminf(m, ap[e] * bf2f((unsigned short)hv[e]) + cp[e]);
#pragma unroll
  for (int off = 1; off < 64; off <<= 1) m = fminf(m, __shfl_xor(m, off));
  if (lane == 0) skip_i[row] = m;
}

__global__ __launch_bounds__(256)
void k_minrow_out(const unsigned short* __restrict__ Ht, const float* __restrict__ A2,
                  const float* __restrict__ C2, const float* __restrict__ skip_i,
                  float* __restrict__ outs, int i) {
  int t = threadIdx.x, lane = t & 63, wid = t >> 6;
  int row = blockIdx.x * 4 + wid;          // b*64 + d
  int b = row >> 6, d = row & 63;
  s16x8 hv = *(const s16x8*)(Ht + (size_t)row * NN + lane * 8);
  const float* ap = A2 + lane * 8;
  const float* cp = C2 + lane * 8;
  float m = 1e30f;
#pragma unroll
  for (int e = 0; e < 8; ++e) m = fminf(m, ap[e] * bf2f((unsigned short)hv[e]) + cp[e]);
#pragma unroll
  for (int off = 1; off < 64; off <<= 1) m = fminf(m, __shfl_xor(m, off));
  if (lane == 0) outs[(size_t)b * 192 + i * 64 + d] = m + skip_i[row];
}

// ---------------- layer2 fused: H2t = relu((adjB@H1 + rc)@W2 + b2), + stats ----------------
__global__ __launch_bounds__(256)
void k_layer2(const unsigned short* __restrict__ H1t, const unsigned short* __restrict__ adjB,
              const float* __restrict__ rc, const unsigned short* __restrict__ W2t_i,
              const float* __restrict__ b2_i, unsigned short* __restrict__ H2t,
              float* __restrict__ Ssum, float* __restrict__ Ssq) {
  __shared__ unsigned short At[64 * LDT];   // H1t rows f, k=m
  __shared__ unsigned short Bt[64 * LDT];   // adjB rows n, k=m
  __shared__ unsigned short Gt[64 * LDT];   // G[n][f] bf16
  __shared__ unsigned short B2[64 * LDT];   // W2t rows d, k=f
  __shared__ float ssum[64], ssq[64];
  int blk = blockIdx.x; int b = blk >> 3; int n0 = (blk & 7) << 6;
  int t = threadIdx.x, lane = t & 63, wid = t >> 6;
  int wi = wid >> 1, wj = wid & 1;
  int r = t >> 2, seg = t & 3;
  if (t < 64) { ssum[t] = 0.f; ssq[t] = 0.f; }
  {
    const unsigned short* s2 = W2t_i + r * 64 + seg * 16;
    *(s16x8*)&B2[r * LDT + seg * 16]     = *(const s16x8*)s2;
    *(s16x8*)&B2[r * LDT + seg * 16 + 8] = *(const s16x8*)(s2 + 8);
  }
  const unsigned short* aSrc = H1t + ((size_t)b * NH + r) * NN + seg * 16;
  const unsigned short* bSrc = adjB + (size_t)(n0 + r) * NN + seg * 16;
  unsigned short* aDst = &At[r * LDT + seg * 16];
  unsigned short* bDst = &Bt[r * LDT + seg * 16];

  f32x4 acc[2][2] = {};
  for (int kt = 0; kt < 8; ++kt) {
    __syncthreads();
    *(s16x8*)aDst = *(const s16x8*)aSrc;  *(s16x8*)(aDst + 8) = *(const s16x8*)(aSrc + 8);
    *(s16x8*)bDst = *(const s16x8*)bSrc;  *(s16x8*)(bDst + 8) = *(const s16x8*)(bSrc + 8);
    aSrc += 64; bSrc += 64;
    __syncthreads();
#pragma unroll
    for (int kk = 0; kk < 2; ++kk) {
      int ko = kk * 32 + (lane >> 4) * 8;
      s16x8 a0 = *(const s16x8*)&At[(wi * 32 +  0 + (lane & 15)) * LDT + ko];
      s16x8 a1 = *(const s16x8*)&At[(wi * 32 + 16 + (lane & 15)) * LDT + ko];
      s16x8 b0 = *(const s16x8*)&Bt[(wj * 32 +  0 + (lane & 15)) * LDT + ko];
      s16x8 b1 = *(const s16x8*)&Bt[(wj * 32 + 16 + (lane & 15)) * LDT + ko];
      acc[0][0] = MFMA16(a0, b0, acc[0][0]);
      acc[1][0] = MFMA16(a1, b0, acc[1][0]);
      acc[0][1] = MFMA16(a0, b1, acc[0][1]);
      acc[1][1] = MFMA16(a1, b1, acc[1][1]);
    }
  }
  // D1[i=f][j=n] + rc[n] -> Gt[n][f] bf16
  int ncol = wj * 32 + (lane & 15);
  float rc0 = rc[n0 + ncol], rc1 = rc[n0 + ncol + 16];
#pragma unroll
  for (int fi = 0; fi < 2; ++fi) {
    int floc = wi * 32 + fi * 16 + (lane >> 4) * 4;
    ushort4 p0, p1;
    p0.x = f2bf(acc[fi][0][0] + rc0); p0.y = f2bf(acc[fi][0][1] + rc0);
    p0.z = f2bf(acc[fi][0][2] + rc0); p0.w = f2bf(acc[fi][0][3] + rc0);
    p1.x = f2bf(acc[fi][1][0] + rc1); p1.y = f2bf(acc[fi][1][1] + rc1);
    p1.z = f2bf(acc[fi][1][2] + rc1); p1.w = f2bf(acc[fi][1][3] + rc1);
    *(ushort4*)&Gt[(ncol)      * LDT + floc] = p0;
    *(ushort4*)&Gt[(ncol + 16) * LDT + floc] = p1;
  }
  __syncthreads();
  // stage2: D2[i=n][j=d] = sum_f Gt[n][f] * W2t[d][f]
  f32x4 acc2[2][2] = {};
#pragma unroll
  for (int kk = 0; kk < 2; ++kk) {
    int ko = kk * 32 + (lane >> 4) * 8;
    s16x8 a0 = *(const s16x8*)&Gt[(wi * 32 +  0 + (lane & 15)) * LDT + ko];
    s16x8 a1 = *(const s16x8*)&Gt[(wi * 32 + 16 + (lane & 15)) * LDT + ko];
    s16x8 b0 = *(const s16x8*)&B2[(wj * 32 +  0 + (lane & 15)) * LDT + ko];
    s16x8 b1 = *(const s16x8*)&B2[(wj * 32 + 16 + (lane & 15)) * LDT + ko];
    acc2[0][0] = MFMA16(a0, b0, acc2[0][0]);
    acc2[1][0] = MFMA16(a1, b0, acc2[1][0]);
    acc2[0][1] = MFMA16(a0, b1, acc2[0][1]);
    acc2[1][1] = MFMA16(a1, b1, acc2[1][1]);
  }
  int dcol = wj * 32 + (lane & 15);
  float bb0 = b2_i[dcol], bb1 = b2_i[dcol + 16];
#pragma unroll
  for (int fi = 0; fi < 2; ++fi) {
    int nloc = wi * 32 + fi * 16 + (lane >> 4) * 4;
    float v0[4], v1[4];
#pragma unroll
    for (int rr = 0; rr < 4; ++rr) {
      float x0 = fmaxf(acc2[fi][0][rr] + bb0, 0.f);
      float x1 = fmaxf(acc2[fi][1][rr] + bb1, 0.f);
      v0[rr] = x0; v1[rr] = x1;
      float sv = x0 + x1, qv = x0 * x0 + x1 * x1;
      sv += __shfl_xor(sv, 1); sv += __shfl_xor(sv, 2); sv += __shfl_xor(sv, 4); sv += __shfl_xor(sv, 8);
      qv += __shfl_xor(qv, 1); qv += __shfl_xor(qv, 2); qv += __shfl_xor(qv, 4); qv += __shfl_xor(qv, 8);
      if ((lane & 15) == 0) { atomicAdd(&ssum[nloc + rr], sv); atomicAdd(&ssq[nloc + rr], qv); }
    }
    ushort4 p0, p1;
    p0.x = f2bf(v0[0]); p0.y = f2bf(v0[1]); p0.z = f2bf(v0[2]); p0.w = f2bf(v0[3]);
    p1.x = f2bf(v1[0]); p1.y = f2bf(v1[1]); p1.z = f2bf(v1[2]); p1.w = f2bf(v1[3]);
    *(ushort4*)&H2t[((size_t)b * NH + dcol)      * NN + n0 + nloc] = p0;
    *(ushort4*)&H2t[((size_t)b * NH + dcol + 16) * NN + n0 + nloc] = p1;
  }
  __syncthreads();
  if (t < 64) { atomicAdd(&Ssum[n0 + t], ssum[t]); atomicAdd(&Ssq[n0 + t], ssq[t]); }
}

// ---------------- final FC: out[b][o] = outs[b][:192] @ Wfc + bfc ----------------
__global__ void k_fc(const float* __restrict__ outs, const float* __restrict__ Wfc,
                     const float* __restrict__ bfc, float* __restrict__ out) {
  int b = blockIdx.x, t = threadIdx.x;
  if (t < 32) {
    float acc = bfc[t];
    const float* orow = outs + (size_t)b * 192;
    for (int j = 0; j < 192; ++j) acc += orow[j] * Wfc[j * 32 + t];
    out[b * 32 + t] = acc;
  }
}

extern "C" void kernel_launch(void* const* d_in, const int* in_sizes, int n_in,
                              void* d_out, int out_size, void* d_ws, size_t ws_size,
                              hipStream_t stream) {
  const float* X   = (const float*)d_in[0];
  const float* adj = (const float*)d_in[1];
  const float* W1  = (const float*)d_in[2];
  const float* b1  = (const float*)d_in[3];
  const float* g1  = (const float*)d_in[4];
  const float* be1 = (const float*)d_in[5];
  const float* W2  = (const float*)d_in[6];
  const float* b2  = (const float*)d_in[7];
  const float* g2  = (const float*)d_in[8];
  const float* be2 = (const float*)d_in[9];
  const float* Wfc = (const float*)d_in[10];
  const float* bfc = (const float*)d_in[11];
  float* out = (float*)d_out;

  char* ws = (char*)d_ws;
  size_t off = 0;
  auto alloc = [&](size_t bytes) {
    char* p = ws + off; off += (bytes + 255) & ~(size_t)255; return p;
  };
  unsigned short* ADJBF = (unsigned short*)alloc(512 * 512 * 2);
  unsigned short* ADJB  = (unsigned short*)alloc(512 * 512 * 2);
  unsigned short* W1T   = (unsigned short*)alloc(3 * 4096 * 2);
  unsigned short* W2T   = (unsigned short*)alloc(3 * 4096 * 2);
  float* SS1 = (float*)alloc(3 * 512 * 4);   // contiguous 4x6144B for one memset
  float* SQ1 = (float*)alloc(3 * 512 * 4);
  float* SS2 = (float*)alloc(3 * 512 * 4);
  float* SQ2 = (float*)alloc(3 * 512 * 4);
  float* A1  = (float*)alloc(3 * 512 * 4);
  float* C1  = (float*)alloc(3 * 512 * 4);
  float* A2  = (float*)alloc(3 * 512 * 4);
  float* C2  = (float*)alloc(3 * 512 * 4);
  float* RC  = (float*)alloc(512 * 4);
  float* SKIP = (float*)alloc(3 * 1024 * 64 * 4);
  float* OUTS = (float*)alloc(1024 * 192 * 4);
  unsigned short* XT  = (unsigned short*)alloc((size_t)1024 * 64 * 512 * 2);  // reused as H1T
  unsigned short* AX  = (unsigned short*)alloc((size_t)1024 * 512 * 64 * 2);
  unsigned short* H2T = (unsigned short*)alloc((size_t)1024 * 64 * 512 * 2);
  unsigned short* H1T = XT;   // Xt dead after k_gemm_ax

  hipMemsetAsync(SS1, 0, 4 * 3 * 512 * 4, stream);

  k_prep_adj<<<1024, 256, 0, stream>>>(adj, ADJBF);
  k_prep_w<<<48, 256, 0, stream>>>(W1, W2, W1T, W2T);
  k_transpose_x<<<8192, 256, 0, stream>>>(X, XT);
  k_gemm_ax<<<8192, 256, 0, stream>>>(XT, ADJBF, AX);

  for (int i = 0; i < 3; ++i) {
    k_h1<<<8192, 256, 0, stream>>>(AX, W1T + i * 4096, b1 + i * 64, H1T,
                                   SS1 + i * 512, SQ1 + i * 512);
    k_finalize<<<2, 256, 0, stream>>>(SS1 + i * 512, SQ1 + i * 512, g1 + i * 512,
                                      be1 + i * 512, A1 + i * 512, C1 + i * 512);
    k_adjb<<<512, 256, 0, stream>>>(ADJBF, A1 + i * 512, C1 + i * 512, ADJB, RC);
    k_minrow_skip<<<16384, 256, 0, stream>>>(H1T, A1 + i * 512, C1 + i * 512,
                                             SKIP + i * 65536);
    k_layer2<<<8192, 256, 0, stream>>>(H1T, ADJB, RC, W2T + i * 4096, b2 + i * 64, H2T,
                                       SS2 + i * 512, SQ2 + i * 512);
    k_finalize<<<2, 256, 0, stream>>>(SS2 + i * 512, SQ2 + i * 512, g2 + i * 512,
                                      be2 + i * 512, A2 + i * 512, C2 + i * 512);
    k_minrow_out<<<16384, 256, 0, stream>>>(H2T, A2 + i * 512, C2 + i * 512,
                                            SKIP + i * 65536, OUTS, i);
  }
  k_fc<<<1024, 64, 0, stream>>>(OUTS, Wfc, bfc, out);
}